// Round 7
// baseline (367.591 us; speedup 1.0000x reference)
//
#include <hip/hip_runtime.h>

// GroupedQueryAttention: B=4,S=2048,D=1024,H=16,HK=4,HD=64,G=4, fp32 in/out.
// R7: attention rebuilt around LDS-bandwidth: 64 q-rows/wave (4-wave blocks,
// 256 q-rows), K-frags register-resident across 4 q-frags -> each K/V LDS
// byte feeds 4x the MFMA. Grid 512 = exactly 2 blocks/CU, single flat phase.
// GEMM/prep side identical to R6 (so they surface in top-5 for next round).

typedef unsigned short u16;
typedef unsigned int   u32;
typedef __bf16 bf16x4 __attribute__((ext_vector_type(4)));
typedef __bf16 bf16x8 __attribute__((ext_vector_type(8)));
typedef float  f32x4  __attribute__((ext_vector_type(4)));

#define MFMA(a,b,c) __builtin_amdgcn_mfma_f32_16x16x32_bf16((a),(b),(c),0,0,0)

#define GLDS(g, l) __builtin_amdgcn_global_load_lds(                          \
    (const __attribute__((address_space(1))) void*)(g),                       \
    (__attribute__((address_space(3))) void*)(l), 16, 0, 0)

#if __has_builtin(__builtin_amdgcn_exp2f)
#define EXP2(x) __builtin_amdgcn_exp2f(x)
#else
#define EXP2(x) exp2f(x)
#endif

__device__ __forceinline__ u16 f2bf(float f){
    u32 u = __builtin_bit_cast(u32, f);
    u += 0x7fffu + ((u >> 16) & 1u);      // RNE
    return (u16)(u >> 16);
}
__device__ __forceinline__ u32 pk2(float a, float b){
#if __has_builtin(__builtin_amdgcn_cvt_pk_bf16_f32)
    auto r = __builtin_amdgcn_cvt_pk_bf16_f32(a, b);
    return __builtin_bit_cast(u32, r);
#else
    return (u32)f2bf(a) | ((u32)f2bf(b) << 16);
#endif
}
__device__ __forceinline__ bf16x8 ldfrag(const u16* p){   // 16B-aligned
    return *(const bf16x8*)p;
}
__device__ __forceinline__ bf16x8 ld2x64(const u16* p){   // 8B-aligned
    bf16x4 lo = *(const bf16x4*)p;
    bf16x4 hi = *(const bf16x4*)(p + 4);
    bf16x8 r;
    r[0]=lo[0]; r[1]=lo[1]; r[2]=lo[2]; r[3]=lo[3];
    r[4]=hi[0]; r[5]=hi[1]; r[6]=hi[2]; r[7]=hi[3];
    return r;
}

// ---------------- prep: cast q/k/v fp32->bf16 + 4 weight transposes ---------
__global__ __launch_bounds__(256) void prep(const float* __restrict__ q,
                                            const float* __restrict__ k,
                                            const float* __restrict__ v,
                                            const float* __restrict__ Wq,
                                            const float* __restrict__ Wk,
                                            const float* __restrict__ Wv,
                                            const float* __restrict__ Wo,
                                            u16* Qc, u16* Kc, u16* Vc,
                                            u16* WqT, u16* WkT, u16* WvT, u16* WoT){
    const int tid = threadIdx.x, bid = blockIdx.x;
    if (bid < 2560){
        __shared__ float T[32][33];
        const float* W; u16* WT; int N, i;
        if (bid < 1024)      { W = Wq; WT = WqT; N = 1024; i = bid; }
        else if (bid < 1280) { W = Wk; WT = WkT; N =  256; i = bid - 1024; }
        else if (bid < 1536) { W = Wv; WT = WvT; N =  256; i = bid - 1280; }
        else                 { W = Wo; WT = WoT; N = 1024; i = bid - 1536; }
        int kt = (i & 31) * 32, nt = (i >> 5) * 32;
        int r = tid >> 3, c = tid & 7;
        float4 vv = *(const float4*)(W + (size_t)(kt + r) * N + nt + c * 4);
        T[r][c*4+0] = vv.x; T[r][c*4+1] = vv.y; T[r][c*4+2] = vv.z; T[r][c*4+3] = vv.w;
        __syncthreads();
        u32 lo = pk2(T[c*4+0][r], T[c*4+1][r]);
        u32 hi = pk2(T[c*4+2][r], T[c*4+3][r]);
        *(uint2*)(WT + (size_t)(nt + r) * 1024 + kt + c * 4) = make_uint2(lo, hi);
    } else {
        int i = bid - 2560;                       // 0..1535
        const float* src = (i < 512) ? q : (i < 1024 ? k : v);
        u16*         dst = (i < 512) ? Qc : (i < 1024 ? Kc : Vc);
        size_t off = (size_t)(i & 511) * 16384;   // floats per block
        const float* s = src + off;
        u16* d = dst + off;
        #pragma unroll
        for (int p = 0; p < 16; ++p){
            int idx = (p * 256 + tid) * 4;
            float4 vv = *(const float4*)(s + idx);
            *(uint2*)(d + idx) = make_uint2(pk2(vv.x, vv.y), pk2(vv.z, vv.w));
        }
    }
}

// ---------------- GEMM body: A[M,K] bf16, B as BT[N][K] bf16, GLDS staging --
// EPI 0: bf16 C[M,N] (*oscale), swapped operands -> packed uint2 stores
// EPI 1: bf16 Vt[(b*256+n)*2048+s], unswapped (s-consecutive packing)
// EPI 2: f32 C[M,N], swapped -> float4 stores
template<int EPI>
__device__ __forceinline__ void gemm_body(const u16* __restrict__ A,
                                          const u16* __restrict__ Bt,
                                          void* __restrict__ Cp,
                                          int N, int K, int m0, int n0,
                                          u16* As, u16* Bs, float oscale){
    const int tid  = threadIdx.x;
    const int wave = tid >> 6, lane = tid & 63;
    const int quad = lane >> 4, l15 = lane & 15;
    const int wm = wave >> 1, wn = wave & 1;
    const int srow = lane >> 3;                   // XOR-swizzled staging
    const int scol = ((lane & 7) ^ srow) * 8;
    const int swz  = l15 & 7;

    f32x4 acc[4][4];
    #pragma unroll
    for (int i = 0; i < 4; ++i)
        #pragma unroll
        for (int j = 0; j < 4; ++j) acc[i][j] = (f32x4){0.f, 0.f, 0.f, 0.f};

    const int nkt = K >> 6;
    for (int kt = 0; kt < nkt; ++kt){
        __syncthreads();
        {
            const u16* ga = A + (size_t)(m0 + wave*32 + srow) * K + kt*64 + scol;
            u16* la = As + (wave*32) * 64;
            #pragma unroll
            for (int p = 0; p < 4; ++p)
                GLDS(ga + (size_t)(p*8) * K, la + p*8*64);
            const u16* gb = Bt + (size_t)(n0 + wave*32 + srow) * K + kt*64 + scol;
            u16* lb = Bs + (wave*32) * 64;
            #pragma unroll
            for (int p = 0; p < 4; ++p)
                GLDS(gb + (size_t)(p*8) * K, lb + p*8*64);
        }
        __syncthreads();
        #pragma unroll
        for (int ks = 0; ks < 2; ++ks){
            bf16x8 af[4], bfr[4];
            #pragma unroll
            for (int mt = 0; mt < 4; ++mt)
                af[mt] = ldfrag(&As[(wm*64 + mt*16 + l15) * 64 +
                                    (((ks*4 + quad) ^ swz) * 8)]);
            #pragma unroll
            for (int nt = 0; nt < 4; ++nt)
                bfr[nt] = ldfrag(&Bs[(wn*64 + nt*16 + l15) * 64 +
                                     (((ks*4 + quad) ^ swz) * 8)]);
            #pragma unroll
            for (int mt = 0; mt < 4; ++mt)
                #pragma unroll
                for (int nt = 0; nt < 4; ++nt){
                    if constexpr (EPI == 1)
                        acc[mt][nt] = MFMA(af[mt], bfr[nt], acc[mt][nt]);
                    else
                        acc[mt][nt] = MFMA(bfr[nt], af[mt], acc[mt][nt]);
                }
        }
    }
    #pragma unroll
    for (int mt = 0; mt < 4; ++mt){
        #pragma unroll
        for (int nt = 0; nt < 4; ++nt){
            if constexpr (EPI == 1){
                // C row = m (A rows) = quad*4+reg; col = n (B rows) = l15
                int rowb = m0 + wm*64 + mt*16 + quad*4;       // s (4 consecutive)
                int col  = n0 + wn*64 + nt*16 + l15;          // n
                u16* C = (u16*)Cp;
                int bb = rowb >> 11, s = rowb & 2047;
                u32 lo = pk2(acc[mt][nt][0], acc[mt][nt][1]);
                u32 hi = pk2(acc[mt][nt][2], acc[mt][nt][3]);
                *(uint2*)(C + (size_t)(bb * 256 + col) * 2048 + s) = make_uint2(lo, hi);
            } else {
                // swapped: C row = A rows = l15; col = B rows = quad*4+reg
                int row  = m0 + wm*64 + mt*16 + l15;
                int colb = n0 + wn*64 + nt*16 + quad*4;
                if constexpr (EPI == 0){
                    u16* C = (u16*)Cp;
                    u32 lo = pk2(acc[mt][nt][0]*oscale, acc[mt][nt][1]*oscale);
                    u32 hi = pk2(acc[mt][nt][2]*oscale, acc[mt][nt][3]*oscale);
                    *(uint2*)(C + (size_t)row * N + colb) = make_uint2(lo, hi);
                } else {
                    float* C = (float*)Cp;
                    *(f32x4*)(C + (size_t)row * N + colb) = acc[mt][nt];
                }
            }
        }
    }
}

// fused Q+K+V projection: 512 Q-blocks + 128 K + 128 V = 768 blocks
__global__ __launch_bounds__(256) void gemm_qkv(const u16* Qc, const u16* WqT, u16* Qp,
                                                const u16* Kc, const u16* WkT, u16* Kp,
                                                const u16* Vc, const u16* WvT, u16* Vt,
                                                float qscale){
    __shared__ u16 As[128 * 64];
    __shared__ u16 Bs[128 * 64];
    int bid = blockIdx.x;
    if (bid < 512)
        gemm_body<0>(Qc, WqT, Qp, 1024, 1024, (bid >> 3) * 128, (bid & 7) * 128,
                     As, Bs, qscale);
    else if (bid < 640){
        int i = bid - 512;
        gemm_body<0>(Kc, WkT, Kp, 256, 1024, (i >> 1) * 128, (i & 1) * 128,
                     As, Bs, 1.0f);
    } else {
        int i = bid - 640;
        gemm_body<1>(Vc, WvT, Vt, 256, 1024, (i >> 1) * 128, (i & 1) * 128,
                     As, Bs, 1.0f);
    }
}

__global__ __launch_bounds__(256) void gemm_o(const u16* AO, const u16* WoT,
                                              float* Out){
    __shared__ u16 As[128 * 64];
    __shared__ u16 Bs[128 * 64];
    int bid = blockIdx.x;
    gemm_body<2>(AO, WoT, Out, 1024, 1024, (bid >> 3) * 128, (bid & 7) * 128,
                 As, Bs, 1.0f);
}

// ---------------- flash attention -------------------------------------------
// grid (8 qtiles, 16 heads, 4 batch) = 512 blocks = 2/CU (one flat phase),
// 256 threads = 4 waves, 64 q-rows/wave (256 q-rows/block).
// S^T = K.Q^T (Q pre-scaled by 0.125*log2e), no-max exp2, row-sums via
// all-ones MFMA, O^T = V^T.P. K-frags register-resident across the 4 q-frags
// (each K/V LDS byte feeds 4 MFMAs). Double-buffered GLDS K/V staging,
// one barrier per kv-tile. LDS = 66 KB -> 2 blocks/CU.
__global__ __launch_bounds__(256) void attn_k(const u16* __restrict__ Qp,
                                              const u16* __restrict__ Kp,
                                              const u16* __restrict__ Vt,
                                              u16* __restrict__ AO){
    constexpr int S = 2048, Dm = 1024, NKV = 256, PST = 68;
    __shared__ u16 Kb[2][64 * 64];
    __shared__ u16 Vb[2][64 * 64];
    __shared__ u16 Ps[256 * PST];        // Q staging, then per-wave P rows
    const int tid = threadIdx.x, wave = tid >> 6, lane = tid & 63;
    const int quad = lane >> 4, l15 = lane & 15;
    const int h = blockIdx.y, b = blockIdx.z;
    const int hk = h >> 2, q0 = blockIdx.x * 256;
    u16* pw = Ps + wave * (64 * PST);    // wave's 64 P rows (== its q rows)

    const int srow = lane >> 3;                   // 0..7
    const int scol = ((lane & 7) ^ srow) * 8;     // swizzled source col
    const int swz  = l15 & 7;                     // row-dependent read XOR

    auto issue = [&](int t){
        int j0 = t * 64, bufi = t & 1;
        #pragma unroll
        for (int p = 0; p < 2; ++p){
            int r = wave * 16 + p * 8 + srow;     // each wave stages 16 rows
            GLDS(Kp + (size_t)(b * S + j0 + r) * NKV + hk * 64 + scol,
                 &Kb[bufi][(wave * 16 + p * 8) * 64]);
            GLDS(Vt + (size_t)(b * NKV + hk * 64 + r) * S + j0 + scol,
                 &Vb[bufi][(wave * 16 + p * 8) * 64]);
        }
    };

    issue(0);                            // start tile-0 loads immediately
    {   // stage Q tile (256 rows x 64) into Ps, stride PST
        int c8 = tid & 7, r0 = tid >> 3;          // r0: 0..31
        #pragma unroll
        for (int p = 0; p < 8; ++p){
            int r = r0 + p * 32;
            uint4 v = *(const uint4*)(Qp + (size_t)(b * S + q0 + r) * Dm + h * 64 + c8 * 8);
            *(uint2*)&Ps[r * PST + c8 * 8]     = make_uint2(v.x, v.y);
            *(uint2*)&Ps[r * PST + c8 * 8 + 4] = make_uint2(v.z, v.w);
        }
    }
    __syncthreads();                     // Q published (also drains tile-0 vm)
    bf16x8 qf[4][2];                     // [mt][ks]; wave's 64 q-rows
    #pragma unroll
    for (int mt = 0; mt < 4; ++mt)
        #pragma unroll
        for (int ks = 0; ks < 2; ++ks)
            qf[mt][ks] = ld2x64(&Ps[(wave*64 + mt*16 + l15) * PST + ks*32 + quad*8]);

    const u32 one2 = 0x3F803F80u;        // bf16 1.0 pair
    const bf16x8 ones = __builtin_bit_cast(bf16x8, make_uint4(one2, one2, one2, one2));

    f32x4 O[4][4];                       // [dt][mt]: O^T tiles (d x q)
    #pragma unroll
    for (int dt = 0; dt < 4; ++dt)
        #pragma unroll
        for (int mt = 0; mt < 4; ++mt) O[dt][mt] = (f32x4){0.f, 0.f, 0.f, 0.f};
    f32x4 sums[4];                       // ones-MFMA row-sum accs
    #pragma unroll
    for (int mt = 0; mt < 4; ++mt) sums[mt] = (f32x4){0.f, 0.f, 0.f, 0.f};

    for (int t = 0; t < 32; ++t){
        __syncthreads();                 // tile t resident; buf[(t+1)&1] free
        if (t < 31) issue(t + 1);        // async into other buffer
        const u16* Kt = Kb[t & 1];
        const u16* Vs = Vb[t & 1];
        // K-frags once into registers (reused by all 4 q-frags)
        bf16x8 ak[2][4];                 // [ks][nt]
        #pragma unroll
        for (int ks = 0; ks < 2; ++ks)
            #pragma unroll
            for (int nt = 0; nt < 4; ++nt)
                ak[ks][nt] = ldfrag(&Kt[(nt*16 + l15) * 64 + (((ks*4 + quad) ^ swz) * 8)]);
        // per q-frag: S^T = K(64kv x 64d).Q^T(64d x 16q), exp2, packed P write
        #pragma unroll
        for (int mt = 0; mt < 4; ++mt){
            f32x4 sf[4];
            #pragma unroll
            for (int nt = 0; nt < 4; ++nt) sf[nt] = (f32x4){0.f, 0.f, 0.f, 0.f};
            #pragma unroll
            for (int ks = 0; ks < 2; ++ks)
                #pragma unroll
                for (int nt = 0; nt < 4; ++nt)
                    sf[nt] = MFMA(ak[ks][nt], qf[mt][ks], sf[nt]);
            #pragma unroll
            for (int nt = 0; nt < 4; ++nt){
                float e0 = EXP2(sf[nt][0]);
                float e1 = EXP2(sf[nt][1]);
                float e2 = EXP2(sf[nt][2]);
                float e3 = EXP2(sf[nt][3]);
                *(uint2*)&pw[(mt*16 + l15) * PST + nt*16 + quad*4] =
                    make_uint2(pk2(e0, e1), pk2(e2, e3));
            }
        }
        __threadfence_block();           // P LDS write->read order (wave-local)
        // O^T += V^T(64d x 64kv) . P(64kv x 64q); sums += ones . P
        #pragma unroll
        for (int ks = 0; ks < 2; ++ks){
            bf16x8 av[4], bp[4];
            #pragma unroll
            for (int dt = 0; dt < 4; ++dt)
                av[dt] = ldfrag(&Vs[(dt*16 + l15) * 64 + (((ks*4 + quad) ^ swz) * 8)]);
            #pragma unroll
            for (int mt = 0; mt < 4; ++mt)
                bp[mt] = ld2x64(&pw[(mt*16 + l15) * PST + ks*32 + quad*8]);
            #pragma unroll
            for (int mt = 0; mt < 4; ++mt)
                sums[mt] = MFMA(ones, bp[mt], sums[mt]);
            #pragma unroll
            for (int dt = 0; dt < 4; ++dt)
                #pragma unroll
                for (int mt = 0; mt < 4; ++mt)
                    O[dt][mt] = MFMA(av[dt], bp[mt], O[dt][mt]);
        }
    }
    // epilogue: every reg/quad of sums[mt] holds the row-sum for its q col
    #pragma unroll
    for (int mt = 0; mt < 4; ++mt){
        float inv = 1.0f / sums[mt][0];
        size_t row = (size_t)(b * S + q0 + wave*64 + mt*16 + l15);
        #pragma unroll
        for (int dt = 0; dt < 4; ++dt){
            u32 lo = pk2(O[dt][mt][0] * inv, O[dt][mt][1] * inv);
            u32 hi = pk2(O[dt][mt][2] * inv, O[dt][mt][3] * inv);
            *(uint2*)(AO + row * Dm + h * 64 + dt*16 + quad*4) = make_uint2(lo, hi);
        }
    }
}

extern "C" void kernel_launch(void* const* d_in, const int* in_sizes, int n_in,
                              void* d_out, int out_size, void* d_ws, size_t ws_size,
                              hipStream_t stream){
    const float* q  = (const float*)d_in[0];
    const float* k  = (const float*)d_in[1];
    const float* v  = (const float*)d_in[2];
    const float* Wq = (const float*)d_in[3];
    const float* Wk = (const float*)d_in[4];
    const float* Wv = (const float*)d_in[5];
    const float* Wo = (const float*)d_in[6];
    char* ws = (char*)d_ws;
    const size_t MB = 1u << 20;
    u16* WqT = (u16*)(ws);               // [1024][1024]  2 MiB
    u16* WkT = (u16*)(ws + 2*MB);        // [ 256][1024]  0.5
    u16* WvT = (u16*)(ws + 2*MB + 512*1024);
    u16* WoT = (u16*)(ws + 3*MB);        // 2 MiB
    u16* Qc  = (u16*)(ws + 5*MB);        // bf16 query  [8192][1024] 16 MiB
    u16* Kc  = (u16*)(ws + 21*MB);       // bf16 key    16 MiB
    u16* Vc  = (u16*)(ws + 37*MB);       // bf16 value  16 MiB
    u16* Qp  = (u16*)(ws + 53*MB);       // Q-proj      16 MiB
    u16* Kp  = (u16*)(ws + 69*MB);       // K-proj       4 MiB
    u16* Vt  = (u16*)(ws + 73*MB);       // V-proj^T     4 MiB
    u16* AO  = (u16*)(ws + 5*MB);        // attn out (aliases Qc, dead by then)

    const float cexp = 0.125f * 1.44269504f;   // softmax scale * log2(e)

    prep<<<dim3(4096), 256, 0, stream>>>(q, k, v, Wq, Wk, Wv, Wo,
                                         Qc, Kc, Vc, WqT, WkT, WvT, WoT);
    gemm_qkv<<<dim3(768), 256, 0, stream>>>(Qc, WqT, Qp, Kc, WkT, Kp,
                                            Vc, WvT, Vt, cexp);
    attn_k<<<dim3(8, 16, 4), 256, 0, stream>>>(Qp, Kp, Vt, AO);
    gemm_o<<<dim3(512), 256, 0, stream>>>(AO, WoT, (float*)d_out);
}

// Round 8
// 314.980 us; speedup vs baseline: 1.1670x; 1.1670x over previous
//
#include <hip/hip_runtime.h>

// GroupedQueryAttention: B=4,S=2048,D=1024,H=16,HK=4,HD=64,G=4, fp32 in/out.
// R8: attention = 512-thread blocks (8 waves), 32 q-rows/wave (256 q/block),
// grid 512 = exactly 2 blocks/CU (one flat phase, 16 waves/CU). K-frags
// reused across 2 q-frags (LDS bytes/q-row 1280 -> 768 vs R6), VGPR capped
// at 128 via __launch_bounds__(512,4) with transient-minimizing structure
// (R7's 172-VGPR / 2-waves-per-SIMD collapse was the regression cause).
// GEMM/prep side identical to R6/R7.

typedef unsigned short u16;
typedef unsigned int   u32;
typedef __bf16 bf16x4 __attribute__((ext_vector_type(4)));
typedef __bf16 bf16x8 __attribute__((ext_vector_type(8)));
typedef float  f32x4  __attribute__((ext_vector_type(4)));

#define MFMA(a,b,c) __builtin_amdgcn_mfma_f32_16x16x32_bf16((a),(b),(c),0,0,0)

#define GLDS(g, l) __builtin_amdgcn_global_load_lds(                          \
    (const __attribute__((address_space(1))) void*)(g),                       \
    (__attribute__((address_space(3))) void*)(l), 16, 0, 0)

#if __has_builtin(__builtin_amdgcn_exp2f)
#define EXP2(x) __builtin_amdgcn_exp2f(x)
#else
#define EXP2(x) exp2f(x)
#endif

__device__ __forceinline__ u16 f2bf(float f){
    u32 u = __builtin_bit_cast(u32, f);
    u += 0x7fffu + ((u >> 16) & 1u);      // RNE
    return (u16)(u >> 16);
}
__device__ __forceinline__ u32 pk2(float a, float b){
#if __has_builtin(__builtin_amdgcn_cvt_pk_bf16_f32)
    auto r = __builtin_amdgcn_cvt_pk_bf16_f32(a, b);
    return __builtin_bit_cast(u32, r);
#else
    return (u32)f2bf(a) | ((u32)f2bf(b) << 16);
#endif
}
__device__ __forceinline__ bf16x8 ldfrag(const u16* p){   // 16B-aligned
    return *(const bf16x8*)p;
}
__device__ __forceinline__ bf16x8 ld2x64(const u16* p){   // 8B-aligned
    bf16x4 lo = *(const bf16x4*)p;
    bf16x4 hi = *(const bf16x4*)(p + 4);
    bf16x8 r;
    r[0]=lo[0]; r[1]=lo[1]; r[2]=lo[2]; r[3]=lo[3];
    r[4]=hi[0]; r[5]=hi[1]; r[6]=hi[2]; r[7]=hi[3];
    return r;
}

// ---------------- prep: cast q/k/v fp32->bf16 + 4 weight transposes ---------
__global__ __launch_bounds__(256) void prep(const float* __restrict__ q,
                                            const float* __restrict__ k,
                                            const float* __restrict__ v,
                                            const float* __restrict__ Wq,
                                            const float* __restrict__ Wk,
                                            const float* __restrict__ Wv,
                                            const float* __restrict__ Wo,
                                            u16* Qc, u16* Kc, u16* Vc,
                                            u16* WqT, u16* WkT, u16* WvT, u16* WoT){
    const int tid = threadIdx.x, bid = blockIdx.x;
    if (bid < 2560){
        __shared__ float T[32][33];
        const float* W; u16* WT; int N, i;
        if (bid < 1024)      { W = Wq; WT = WqT; N = 1024; i = bid; }
        else if (bid < 1280) { W = Wk; WT = WkT; N =  256; i = bid - 1024; }
        else if (bid < 1536) { W = Wv; WT = WvT; N =  256; i = bid - 1280; }
        else                 { W = Wo; WT = WoT; N = 1024; i = bid - 1536; }
        int kt = (i & 31) * 32, nt = (i >> 5) * 32;
        int r = tid >> 3, c = tid & 7;
        float4 vv = *(const float4*)(W + (size_t)(kt + r) * N + nt + c * 4);
        T[r][c*4+0] = vv.x; T[r][c*4+1] = vv.y; T[r][c*4+2] = vv.z; T[r][c*4+3] = vv.w;
        __syncthreads();
        u32 lo = pk2(T[c*4+0][r], T[c*4+1][r]);
        u32 hi = pk2(T[c*4+2][r], T[c*4+3][r]);
        *(uint2*)(WT + (size_t)(nt + r) * 1024 + kt + c * 4) = make_uint2(lo, hi);
    } else {
        int i = bid - 2560;                       // 0..1535
        const float* src = (i < 512) ? q : (i < 1024 ? k : v);
        u16*         dst = (i < 512) ? Qc : (i < 1024 ? Kc : Vc);
        size_t off = (size_t)(i & 511) * 16384;   // floats per block
        const float* s = src + off;
        u16* d = dst + off;
        #pragma unroll
        for (int p = 0; p < 16; ++p){
            int idx = (p * 256 + tid) * 4;
            float4 vv = *(const float4*)(s + idx);
            *(uint2*)(d + idx) = make_uint2(pk2(vv.x, vv.y), pk2(vv.z, vv.w));
        }
    }
}

// ---------------- GEMM body: A[M,K] bf16, B as BT[N][K] bf16, GLDS staging --
// EPI 0: bf16 C[M,N] (*oscale), swapped operands -> packed uint2 stores
// EPI 1: bf16 Vt[(b*256+n)*2048+s], unswapped (s-consecutive packing)
// EPI 2: f32 C[M,N], swapped -> float4 stores
template<int EPI>
__device__ __forceinline__ void gemm_body(const u16* __restrict__ A,
                                          const u16* __restrict__ Bt,
                                          void* __restrict__ Cp,
                                          int N, int K, int m0, int n0,
                                          u16* As, u16* Bs, float oscale){
    const int tid  = threadIdx.x;
    const int wave = tid >> 6, lane = tid & 63;
    const int quad = lane >> 4, l15 = lane & 15;
    const int wm = wave >> 1, wn = wave & 1;
    const int srow = lane >> 3;                   // XOR-swizzled staging
    const int scol = ((lane & 7) ^ srow) * 8;
    const int swz  = l15 & 7;

    f32x4 acc[4][4];
    #pragma unroll
    for (int i = 0; i < 4; ++i)
        #pragma unroll
        for (int j = 0; j < 4; ++j) acc[i][j] = (f32x4){0.f, 0.f, 0.f, 0.f};

    const int nkt = K >> 6;
    for (int kt = 0; kt < nkt; ++kt){
        __syncthreads();
        {
            const u16* ga = A + (size_t)(m0 + wave*32 + srow) * K + kt*64 + scol;
            u16* la = As + (wave*32) * 64;
            #pragma unroll
            for (int p = 0; p < 4; ++p)
                GLDS(ga + (size_t)(p*8) * K, la + p*8*64);
            const u16* gb = Bt + (size_t)(n0 + wave*32 + srow) * K + kt*64 + scol;
            u16* lb = Bs + (wave*32) * 64;
            #pragma unroll
            for (int p = 0; p < 4; ++p)
                GLDS(gb + (size_t)(p*8) * K, lb + p*8*64);
        }
        __syncthreads();
        #pragma unroll
        for (int ks = 0; ks < 2; ++ks){
            bf16x8 af[4], bfr[4];
            #pragma unroll
            for (int mt = 0; mt < 4; ++mt)
                af[mt] = ldfrag(&As[(wm*64 + mt*16 + l15) * 64 +
                                    (((ks*4 + quad) ^ swz) * 8)]);
            #pragma unroll
            for (int nt = 0; nt < 4; ++nt)
                bfr[nt] = ldfrag(&Bs[(wn*64 + nt*16 + l15) * 64 +
                                     (((ks*4 + quad) ^ swz) * 8)]);
            #pragma unroll
            for (int mt = 0; mt < 4; ++mt)
                #pragma unroll
                for (int nt = 0; nt < 4; ++nt){
                    if constexpr (EPI == 1)
                        acc[mt][nt] = MFMA(af[mt], bfr[nt], acc[mt][nt]);
                    else
                        acc[mt][nt] = MFMA(bfr[nt], af[mt], acc[mt][nt]);
                }
        }
    }
    #pragma unroll
    for (int mt = 0; mt < 4; ++mt){
        #pragma unroll
        for (int nt = 0; nt < 4; ++nt){
            if constexpr (EPI == 1){
                // C row = m (A rows) = quad*4+reg; col = n (B rows) = l15
                int rowb = m0 + wm*64 + mt*16 + quad*4;       // s (4 consecutive)
                int col  = n0 + wn*64 + nt*16 + l15;          // n
                u16* C = (u16*)Cp;
                int bb = rowb >> 11, s = rowb & 2047;
                u32 lo = pk2(acc[mt][nt][0], acc[mt][nt][1]);
                u32 hi = pk2(acc[mt][nt][2], acc[mt][nt][3]);
                *(uint2*)(C + (size_t)(bb * 256 + col) * 2048 + s) = make_uint2(lo, hi);
            } else {
                // swapped: C row = A rows = l15; col = B rows = quad*4+reg
                int row  = m0 + wm*64 + mt*16 + l15;
                int colb = n0 + wn*64 + nt*16 + quad*4;
                if constexpr (EPI == 0){
                    u16* C = (u16*)Cp;
                    u32 lo = pk2(acc[mt][nt][0]*oscale, acc[mt][nt][1]*oscale);
                    u32 hi = pk2(acc[mt][nt][2]*oscale, acc[mt][nt][3]*oscale);
                    *(uint2*)(C + (size_t)row * N + colb) = make_uint2(lo, hi);
                } else {
                    float* C = (float*)Cp;
                    *(f32x4*)(C + (size_t)row * N + colb) = acc[mt][nt];
                }
            }
        }
    }
}

// fused Q+K+V projection: 512 Q-blocks + 128 K + 128 V = 768 blocks
__global__ __launch_bounds__(256) void gemm_qkv(const u16* Qc, const u16* WqT, u16* Qp,
                                                const u16* Kc, const u16* WkT, u16* Kp,
                                                const u16* Vc, const u16* WvT, u16* Vt,
                                                float qscale){
    __shared__ u16 As[128 * 64];
    __shared__ u16 Bs[128 * 64];
    int bid = blockIdx.x;
    if (bid < 512)
        gemm_body<0>(Qc, WqT, Qp, 1024, 1024, (bid >> 3) * 128, (bid & 7) * 128,
                     As, Bs, qscale);
    else if (bid < 640){
        int i = bid - 512;
        gemm_body<0>(Kc, WkT, Kp, 256, 1024, (i >> 1) * 128, (i & 1) * 128,
                     As, Bs, 1.0f);
    } else {
        int i = bid - 640;
        gemm_body<1>(Vc, WvT, Vt, 256, 1024, (i >> 1) * 128, (i & 1) * 128,
                     As, Bs, 1.0f);
    }
}

__global__ __launch_bounds__(256) void gemm_o(const u16* AO, const u16* WoT,
                                              float* Out){
    __shared__ u16 As[128 * 64];
    __shared__ u16 Bs[128 * 64];
    int bid = blockIdx.x;
    gemm_body<2>(AO, WoT, Out, 1024, 1024, (bid >> 3) * 128, (bid & 7) * 128,
                 As, Bs, 1.0f);
}

// ---------------- flash attention -------------------------------------------
// grid (8 qtiles, 16 heads, 4 batch) = 512 blocks = 2/CU (one flat phase),
// 512 threads = 8 waves, 32 q-rows/wave (256 q-rows/block), 16 waves/CU.
// S^T = K.Q^T (Q pre-scaled by 0.125*log2e), no-max exp2, row-sums via
// all-ones MFMA, O^T = V^T.P. K/V frags feed 2 q-frags each. Double-buffered
// GLDS K/V staging, one barrier per kv-tile. LDS 66.8 KB -> 2 blocks/CU.
// VGPR capped at 128 (4 waves/SIMD) -- transients kept per-ks to fit.
__global__ __launch_bounds__(512, 4) void attn_k(const u16* __restrict__ Qp,
                                                 const u16* __restrict__ Kp,
                                                 const u16* __restrict__ Vt,
                                                 u16* __restrict__ AO){
    constexpr int S = 2048, Dm = 1024, NKV = 256, PST = 68;
    __shared__ u16 Kb[2][64 * 64];
    __shared__ u16 Vb[2][64 * 64];
    __shared__ u16 Ps[256 * PST];        // Q staging, then per-wave P rows
    const int tid = threadIdx.x, wave = tid >> 6, lane = tid & 63;
    const int quad = lane >> 4, l15 = lane & 15;
    const int h = blockIdx.y, b = blockIdx.z;
    const int hk = h >> 2, q0 = blockIdx.x * 256;
    u16* pw = Ps + wave * (32 * PST);    // wave's 32 P rows (== its q rows)

    const int srow = lane >> 3;                   // 0..7
    const int scol = ((lane & 7) ^ srow) * 8;     // swizzled source col
    const int swz  = l15 & 7;                     // row-dependent read XOR

    auto issue = [&](int t){
        int j0 = t * 64, bufi = t & 1;
        int r = wave * 8 + srow;                  // each wave stages 8 rows
        GLDS(Kp + (size_t)(b * S + j0 + r) * NKV + hk * 64 + scol,
             &Kb[bufi][wave * 8 * 64]);
        GLDS(Vt + (size_t)(b * NKV + hk * 64 + r) * S + j0 + scol,
             &Vb[bufi][wave * 8 * 64]);
    };

    issue(0);                            // start tile-0 loads immediately
    {   // stage Q tile (256 rows x 64) into Ps, stride PST
        int c8 = tid & 7, r0 = tid >> 3;          // r0: 0..63
        #pragma unroll
        for (int p = 0; p < 4; ++p){
            int r = r0 + p * 64;
            uint4 v = *(const uint4*)(Qp + (size_t)(b * S + q0 + r) * Dm + h * 64 + c8 * 8);
            *(uint2*)&Ps[r * PST + c8 * 8]     = make_uint2(v.x, v.y);
            *(uint2*)&Ps[r * PST + c8 * 8 + 4] = make_uint2(v.z, v.w);
        }
    }
    __syncthreads();                     // Q published (also drains tile-0 vm)
    bf16x8 qf[2][2];                     // [mt][ks]; wave's 32 q-rows
    #pragma unroll
    for (int mt = 0; mt < 2; ++mt)
        #pragma unroll
        for (int ks = 0; ks < 2; ++ks)
            qf[mt][ks] = ld2x64(&Ps[(wave*32 + mt*16 + l15) * PST + ks*32 + quad*8]);

    const u32 one2 = 0x3F803F80u;        // bf16 1.0 pair
    const bf16x8 ones = __builtin_bit_cast(bf16x8, make_uint4(one2, one2, one2, one2));

    f32x4 O[4][2];                       // [dt][mt]: O^T tiles (d x q)
    #pragma unroll
    for (int dt = 0; dt < 4; ++dt)
        #pragma unroll
        for (int mt = 0; mt < 2; ++mt) O[dt][mt] = (f32x4){0.f, 0.f, 0.f, 0.f};
    f32x4 sums[2];                       // ones-MFMA row-sum accs
    #pragma unroll
    for (int mt = 0; mt < 2; ++mt) sums[mt] = (f32x4){0.f, 0.f, 0.f, 0.f};

    for (int t = 0; t < 32; ++t){
        __syncthreads();                 // tile t resident; buf[(t+1)&1] free
        if (t < 31) issue(t + 1);        // async into other buffer
        const u16* Kt = Kb[t & 1];
        const u16* Vs = Vb[t & 1];
        // S^T = K(64kv x 64d) . Q^T(64d x 32q); ak transient per-ks (VGPR cap)
        f32x4 sf[2][4];                  // [mt][nt]
        #pragma unroll
        for (int mt = 0; mt < 2; ++mt)
            #pragma unroll
            for (int nt = 0; nt < 4; ++nt) sf[mt][nt] = (f32x4){0.f, 0.f, 0.f, 0.f};
        #pragma unroll
        for (int ks = 0; ks < 2; ++ks){
            bf16x8 ak[4];
            #pragma unroll
            for (int nt = 0; nt < 4; ++nt)
                ak[nt] = ldfrag(&Kt[(nt*16 + l15) * 64 + (((ks*4 + quad) ^ swz) * 8)]);
            #pragma unroll
            for (int mt = 0; mt < 2; ++mt)
                #pragma unroll
                for (int nt = 0; nt < 4; ++nt)
                    sf[mt][nt] = MFMA(ak[nt], qf[mt][ks], sf[mt][nt]);
        }
        // lane holds (kv = nt*16+quad*4+r, q = mt*16+l15): exp2, packed P
        #pragma unroll
        for (int mt = 0; mt < 2; ++mt)
            #pragma unroll
            for (int nt = 0; nt < 4; ++nt){
                float e0 = EXP2(sf[mt][nt][0]);
                float e1 = EXP2(sf[mt][nt][1]);
                float e2 = EXP2(sf[mt][nt][2]);
                float e3 = EXP2(sf[mt][nt][3]);
                *(uint2*)&pw[(mt*16 + l15) * PST + nt*16 + quad*4] =
                    make_uint2(pk2(e0, e1), pk2(e2, e3));
            }
        __threadfence_block();           // P LDS write->read order (wave-local)
        // O^T += V^T(64d x 64kv) . P(64kv x 32q); sums += ones . P
        #pragma unroll
        for (int ks = 0; ks < 2; ++ks){
            bf16x8 av[4], bp[2];
            #pragma unroll
            for (int dt = 0; dt < 4; ++dt)
                av[dt] = ldfrag(&Vs[(dt*16 + l15) * 64 + (((ks*4 + quad) ^ swz) * 8)]);
            #pragma unroll
            for (int mt = 0; mt < 2; ++mt)
                bp[mt] = ld2x64(&pw[(mt*16 + l15) * PST + ks*32 + quad*8]);
            #pragma unroll
            for (int mt = 0; mt < 2; ++mt)
                sums[mt] = MFMA(ones, bp[mt], sums[mt]);
            #pragma unroll
            for (int dt = 0; dt < 4; ++dt)
                #pragma unroll
                for (int mt = 0; mt < 2; ++mt)
                    O[dt][mt] = MFMA(av[dt], bp[mt], O[dt][mt]);
        }
    }
    // epilogue: every reg/quad of sums[mt] holds the row-sum for its q col
    #pragma unroll
    for (int mt = 0; mt < 2; ++mt){
        float inv = 1.0f / sums[mt][0];
        size_t row = (size_t)(b * S + q0 + wave*32 + mt*16 + l15);
        #pragma unroll
        for (int dt = 0; dt < 4; ++dt){
            u32 lo = pk2(O[dt][mt][0] * inv, O[dt][mt][1] * inv);
            u32 hi = pk2(O[dt][mt][2] * inv, O[dt][mt][3] * inv);
            *(uint2*)(AO + row * Dm + h * 64 + dt*16 + quad*4) = make_uint2(lo, hi);
        }
    }
}

extern "C" void kernel_launch(void* const* d_in, const int* in_sizes, int n_in,
                              void* d_out, int out_size, void* d_ws, size_t ws_size,
                              hipStream_t stream){
    const float* q  = (const float*)d_in[0];
    const float* k  = (const float*)d_in[1];
    const float* v  = (const float*)d_in[2];
    const float* Wq = (const float*)d_in[3];
    const float* Wk = (const float*)d_in[4];
    const float* Wv = (const float*)d_in[5];
    const float* Wo = (const float*)d_in[6];
    char* ws = (char*)d_ws;
    const size_t MB = 1u << 20;
    u16* WqT = (u16*)(ws);               // [1024][1024]  2 MiB
    u16* WkT = (u16*)(ws + 2*MB);        // [ 256][1024]  0.5
    u16* WvT = (u16*)(ws + 2*MB + 512*1024);
    u16* WoT = (u16*)(ws + 3*MB);        // 2 MiB
    u16* Qc  = (u16*)(ws + 5*MB);        // bf16 query  [8192][1024] 16 MiB
    u16* Kc  = (u16*)(ws + 21*MB);       // bf16 key    16 MiB
    u16* Vc  = (u16*)(ws + 37*MB);       // bf16 value  16 MiB
    u16* Qp  = (u16*)(ws + 53*MB);       // Q-proj      16 MiB
    u16* Kp  = (u16*)(ws + 69*MB);       // K-proj       4 MiB
    u16* Vt  = (u16*)(ws + 73*MB);       // V-proj^T     4 MiB
    u16* AO  = (u16*)(ws + 5*MB);        // attn out (aliases Qc, dead by then)

    const float cexp = 0.125f * 1.44269504f;   // softmax scale * log2(e)

    prep<<<dim3(4096), 256, 0, stream>>>(q, k, v, Wq, Wk, Wv, Wo,
                                         Qc, Kc, Vc, WqT, WkT, WvT, WoT);
    gemm_qkv<<<dim3(768), 256, 0, stream>>>(Qc, WqT, Qp, Kc, WkT, Kp,
                                            Vc, WvT, Vt, cexp);
    attn_k<<<dim3(8, 16, 4), 512, 0, stream>>>(Qp, Kp, Vt, AO);
    gemm_o<<<dim3(512), 256, 0, stream>>>(AO, WoT, (float*)d_out);
}

// Round 9
// 312.278 us; speedup vs baseline: 1.1771x; 1.0087x over previous
//
#include <hip/hip_runtime.h>

// GroupedQueryAttention: B=4,S=2048,D=1024,H=16,HK=4,HD=64,G=4, fp32 in/out.
// R9: activation precast folded back into GEMM A-staging (saves ~192 MB of
// intermediate traffic + a dispatch); prep is now weights-only transpose.
// gemm_qkv becomes a single ~100+ us dispatch so its counters surface in the
// top-5 next round (GEMM side has been an uninstrumented ~210 us since R2).
// attn (R8 structure, 102 us) and gemm_o unchanged as controls.

typedef unsigned short u16;
typedef unsigned int   u32;
typedef __bf16 bf16x4 __attribute__((ext_vector_type(4)));
typedef __bf16 bf16x8 __attribute__((ext_vector_type(8)));
typedef float  f32x4  __attribute__((ext_vector_type(4)));

#define MFMA(a,b,c) __builtin_amdgcn_mfma_f32_16x16x32_bf16((a),(b),(c),0,0,0)

#define GLDS(g, l) __builtin_amdgcn_global_load_lds(                          \
    (const __attribute__((address_space(1))) void*)(g),                       \
    (__attribute__((address_space(3))) void*)(l), 16, 0, 0)

#if __has_builtin(__builtin_amdgcn_exp2f)
#define EXP2(x) __builtin_amdgcn_exp2f(x)
#else
#define EXP2(x) exp2f(x)
#endif

__device__ __forceinline__ u16 f2bf(float f){
    u32 u = __builtin_bit_cast(u32, f);
    u += 0x7fffu + ((u >> 16) & 1u);      // RNE
    return (u16)(u >> 16);
}
__device__ __forceinline__ u32 pk2(float a, float b){
#if __has_builtin(__builtin_amdgcn_cvt_pk_bf16_f32)
    auto r = __builtin_amdgcn_cvt_pk_bf16_f32(a, b);
    return __builtin_bit_cast(u32, r);
#else
    return (u32)f2bf(a) | ((u32)f2bf(b) << 16);
#endif
}
__device__ __forceinline__ bf16x8 ldfrag(const u16* p){   // 16B-aligned
    return *(const bf16x8*)p;
}
__device__ __forceinline__ bf16x8 ld2x64(const u16* p){   // 8B-aligned
    bf16x4 lo = *(const bf16x4*)p;
    bf16x4 hi = *(const bf16x4*)(p + 4);
    bf16x8 r;
    r[0]=lo[0]; r[1]=lo[1]; r[2]=lo[2]; r[3]=lo[3];
    r[4]=hi[0]; r[5]=hi[1]; r[6]=hi[2]; r[7]=hi[3];
    return r;
}

// ---------------- prep: 4 weight transposes W[K][N] f32 -> WT[N][K] bf16 ----
__global__ __launch_bounds__(256) void prep(const float* __restrict__ Wq,
                                            const float* __restrict__ Wk,
                                            const float* __restrict__ Wv,
                                            const float* __restrict__ Wo,
                                            u16* WqT, u16* WkT, u16* WvT, u16* WoT){
    const int tid = threadIdx.x, bid = blockIdx.x;
    __shared__ float T[32][33];
    const float* W; u16* WT; int N, i;
    if (bid < 1024)      { W = Wq; WT = WqT; N = 1024; i = bid; }
    else if (bid < 1280) { W = Wk; WT = WkT; N =  256; i = bid - 1024; }
    else if (bid < 1536) { W = Wv; WT = WvT; N =  256; i = bid - 1280; }
    else                 { W = Wo; WT = WoT; N = 1024; i = bid - 1536; }
    int kt = (i & 31) * 32, nt = (i >> 5) * 32;
    int r = tid >> 3, c = tid & 7;
    float4 vv = *(const float4*)(W + (size_t)(kt + r) * N + nt + c * 4);
    T[r][c*4+0] = vv.x; T[r][c*4+1] = vv.y; T[r][c*4+2] = vv.z; T[r][c*4+3] = vv.w;
    __syncthreads();
    u32 lo = pk2(T[c*4+0][r], T[c*4+1][r]);
    u32 hi = pk2(T[c*4+2][r], T[c*4+3][r]);
    *(uint2*)(WT + (size_t)(nt + r) * 1024 + kt + c * 4) = make_uint2(lo, hi);
}

// ---------------- GEMM body: B as BT[N][K] bf16 (GLDS+swizzle) --------------
// ATYPE 0: A fp32, converted in staging (As stride 80, padded, unswizzled)
// ATYPE 1: A bf16 via GLDS (As stride 64, XOR-swizzled)
// EPI 0: bf16 C[M,N] (*oscale), swapped operands -> packed uint2 stores
// EPI 1: bf16 Vt[(b*256+n)*2048+s], unswapped (s-consecutive packing)
// EPI 2: f32 C[M,N], swapped -> float4 stores
template<int ATYPE, int EPI>
__device__ __forceinline__ void gemm_body(const void* __restrict__ Ap,
                                          const u16* __restrict__ Bt,
                                          void* __restrict__ Cp,
                                          int N, int K, int m0, int n0,
                                          u16* As, u16* Bs, float oscale){
    constexpr int ASTR = (ATYPE == 0) ? 80 : 64;
    const int tid  = threadIdx.x;
    const int wave = tid >> 6, lane = tid & 63;
    const int quad = lane >> 4, l15 = lane & 15;
    const int wm = wave >> 1, wn = wave & 1;
    const int srow = lane >> 3;                   // XOR-swizzled staging
    const int scol = ((lane & 7) ^ srow) * 8;
    const int swz  = l15 & 7;

    f32x4 acc[4][4];
    #pragma unroll
    for (int i = 0; i < 4; ++i)
        #pragma unroll
        for (int j = 0; j < 4; ++j) acc[i][j] = (f32x4){0.f, 0.f, 0.f, 0.f};

    const int nkt = K >> 6;
    for (int kt = 0; kt < nkt; ++kt){
        __syncthreads();
        if constexpr (ATYPE == 0){
            const float* A = (const float*)Ap;
            int c4 = tid & 15, r0 = tid >> 4;
            #pragma unroll
            for (int p = 0; p < 8; ++p){
                int r = r0 + p * 16;
                float4 v = *(const float4*)(A + (size_t)(m0 + r) * K + kt * 64 + c4 * 4);
                *(uint2*)&As[r * 80 + c4 * 4] = make_uint2(pk2(v.x, v.y), pk2(v.z, v.w));
            }
        } else {
            const u16* A = (const u16*)Ap;
            const u16* ga = A + (size_t)(m0 + wave*32 + srow) * K + kt*64 + scol;
            u16* la = As + (wave*32) * 64;
            #pragma unroll
            for (int p = 0; p < 4; ++p)
                GLDS(ga + (size_t)(p*8) * K, la + p*8*64);
        }
        {
            const u16* gb = Bt + (size_t)(n0 + wave*32 + srow) * K + kt*64 + scol;
            u16* lb = Bs + (wave*32) * 64;
            #pragma unroll
            for (int p = 0; p < 4; ++p)
                GLDS(gb + (size_t)(p*8) * K, lb + p*8*64);
        }
        __syncthreads();
        #pragma unroll
        for (int ks = 0; ks < 2; ++ks){
            bf16x8 af[4], bfr[4];
            #pragma unroll
            for (int mt = 0; mt < 4; ++mt){
                if constexpr (ATYPE == 0)
                    af[mt] = ldfrag(&As[(wm*64 + mt*16 + l15) * 80 + ks*32 + quad*8]);
                else
                    af[mt] = ldfrag(&As[(wm*64 + mt*16 + l15) * 64 +
                                        (((ks*4 + quad) ^ swz) * 8)]);
            }
            #pragma unroll
            for (int nt = 0; nt < 4; ++nt)
                bfr[nt] = ldfrag(&Bs[(wn*64 + nt*16 + l15) * 64 +
                                     (((ks*4 + quad) ^ swz) * 8)]);
            #pragma unroll
            for (int mt = 0; mt < 4; ++mt)
                #pragma unroll
                for (int nt = 0; nt < 4; ++nt){
                    if constexpr (EPI == 1)
                        acc[mt][nt] = MFMA(af[mt], bfr[nt], acc[mt][nt]);
                    else
                        acc[mt][nt] = MFMA(bfr[nt], af[mt], acc[mt][nt]);
                }
        }
    }
    #pragma unroll
    for (int mt = 0; mt < 4; ++mt){
        #pragma unroll
        for (int nt = 0; nt < 4; ++nt){
            if constexpr (EPI == 1){
                // unswapped: C row = quad*4+reg (s, 4 consecutive); col = l15
                int rowb = m0 + wm*64 + mt*16 + quad*4;
                int col  = n0 + wn*64 + nt*16 + l15;
                u16* C = (u16*)Cp;
                int bb = rowb >> 11, s = rowb & 2047;
                u32 lo = pk2(acc[mt][nt][0], acc[mt][nt][1]);
                u32 hi = pk2(acc[mt][nt][2], acc[mt][nt][3]);
                *(uint2*)(C + (size_t)(bb * 256 + col) * 2048 + s) = make_uint2(lo, hi);
            } else {
                // swapped: C row = A rows = l15; col = B rows = quad*4+reg
                int row  = m0 + wm*64 + mt*16 + l15;
                int colb = n0 + wn*64 + nt*16 + quad*4;
                if constexpr (EPI == 0){
                    u16* C = (u16*)Cp;
                    u32 lo = pk2(acc[mt][nt][0]*oscale, acc[mt][nt][1]*oscale);
                    u32 hi = pk2(acc[mt][nt][2]*oscale, acc[mt][nt][3]*oscale);
                    *(uint2*)(C + (size_t)row * N + colb) = make_uint2(lo, hi);
                } else {
                    float* C = (float*)Cp;
                    *(f32x4*)(C + (size_t)row * N + colb) = acc[mt][nt];
                }
            }
        }
    }
}

// fused Q+K+V projection (A = raw fp32 activations, converted in staging):
// 512 Q-blocks + 128 K + 128 V = 768 blocks
__global__ __launch_bounds__(256) void gemm_qkv(const float* q, const u16* WqT, u16* Qp,
                                                const float* k, const u16* WkT, u16* Kp,
                                                const float* v, const u16* WvT, u16* Vt,
                                                float qscale){
    __shared__ u16 As[128 * 80];
    __shared__ u16 Bs[128 * 64];
    int bid = blockIdx.x;
    if (bid < 512)
        gemm_body<0,0>((const void*)q, WqT, (void*)Qp, 1024, 1024,
                       (bid >> 3) * 128, (bid & 7) * 128, As, Bs, qscale);
    else if (bid < 640){
        int i = bid - 512;
        gemm_body<0,0>((const void*)k, WkT, (void*)Kp, 256, 1024,
                       (i >> 1) * 128, (i & 1) * 128, As, Bs, 1.0f);
    } else {
        int i = bid - 640;
        gemm_body<0,1>((const void*)v, WvT, (void*)Vt, 256, 1024,
                       (i >> 1) * 128, (i & 1) * 128, As, Bs, 1.0f);
    }
}

__global__ __launch_bounds__(256) void gemm_o(const u16* AO, const u16* WoT,
                                              float* Out){
    __shared__ u16 As[128 * 64];
    __shared__ u16 Bs[128 * 64];
    int bid = blockIdx.x;
    gemm_body<1,2>((const void*)AO, WoT, (void*)Out, 1024, 1024,
                   (bid >> 3) * 128, (bid & 7) * 128, As, Bs, 1.0f);
}

// ---------------- flash attention (R8 structure, unchanged) -----------------
// grid (8 qtiles, 16 heads, 4 batch) = 512 blocks = 2/CU (one flat phase),
// 512 threads = 8 waves, 32 q-rows/wave (256 q-rows/block), 16 waves/CU.
// S^T = K.Q^T (Q pre-scaled by 0.125*log2e), no-max exp2, row-sums via
// all-ones MFMA, O^T = V^T.P. Double-buffered GLDS K/V staging, one barrier
// per kv-tile. LDS 66.8 KB -> 2 blocks/CU. VGPR capped at 128.
__global__ __launch_bounds__(512, 4) void attn_k(const u16* __restrict__ Qp,
                                                 const u16* __restrict__ Kp,
                                                 const u16* __restrict__ Vt,
                                                 u16* __restrict__ AO){
    constexpr int S = 2048, Dm = 1024, NKV = 256, PST = 68;
    __shared__ u16 Kb[2][64 * 64];
    __shared__ u16 Vb[2][64 * 64];
    __shared__ u16 Ps[256 * PST];        // Q staging, then per-wave P rows
    const int tid = threadIdx.x, wave = tid >> 6, lane = tid & 63;
    const int quad = lane >> 4, l15 = lane & 15;
    const int h = blockIdx.y, b = blockIdx.z;
    const int hk = h >> 2, q0 = blockIdx.x * 256;
    u16* pw = Ps + wave * (32 * PST);    // wave's 32 P rows (== its q rows)

    const int srow = lane >> 3;                   // 0..7
    const int scol = ((lane & 7) ^ srow) * 8;     // swizzled source col
    const int swz  = l15 & 7;                     // row-dependent read XOR

    auto issue = [&](int t){
        int j0 = t * 64, bufi = t & 1;
        int r = wave * 8 + srow;                  // each wave stages 8 rows
        GLDS(Kp + (size_t)(b * S + j0 + r) * NKV + hk * 64 + scol,
             &Kb[bufi][wave * 8 * 64]);
        GLDS(Vt + (size_t)(b * NKV + hk * 64 + r) * S + j0 + scol,
             &Vb[bufi][wave * 8 * 64]);
    };

    issue(0);                            // start tile-0 loads immediately
    {   // stage Q tile (256 rows x 64) into Ps, stride PST
        int c8 = tid & 7, r0 = tid >> 3;          // r0: 0..63
        #pragma unroll
        for (int p = 0; p < 4; ++p){
            int r = r0 + p * 64;
            uint4 v = *(const uint4*)(Qp + (size_t)(b * S + q0 + r) * Dm + h * 64 + c8 * 8);
            *(uint2*)&Ps[r * PST + c8 * 8]     = make_uint2(v.x, v.y);
            *(uint2*)&Ps[r * PST + c8 * 8 + 4] = make_uint2(v.z, v.w);
        }
    }
    __syncthreads();                     // Q published (also drains tile-0 vm)
    bf16x8 qf[2][2];                     // [mt][ks]; wave's 32 q-rows
    #pragma unroll
    for (int mt = 0; mt < 2; ++mt)
        #pragma unroll
        for (int ks = 0; ks < 2; ++ks)
            qf[mt][ks] = ld2x64(&Ps[(wave*32 + mt*16 + l15) * PST + ks*32 + quad*8]);

    const u32 one2 = 0x3F803F80u;        // bf16 1.0 pair
    const bf16x8 ones = __builtin_bit_cast(bf16x8, make_uint4(one2, one2, one2, one2));

    f32x4 O[4][2];                       // [dt][mt]: O^T tiles (d x q)
    #pragma unroll
    for (int dt = 0; dt < 4; ++dt)
        #pragma unroll
        for (int mt = 0; mt < 2; ++mt) O[dt][mt] = (f32x4){0.f, 0.f, 0.f, 0.f};
    f32x4 sums[2];                       // ones-MFMA row-sum accs
    #pragma unroll
    for (int mt = 0; mt < 2; ++mt) sums[mt] = (f32x4){0.f, 0.f, 0.f, 0.f};

    for (int t = 0; t < 32; ++t){
        __syncthreads();                 // tile t resident; buf[(t+1)&1] free
        if (t < 31) issue(t + 1);        // async into other buffer
        const u16* Kt = Kb[t & 1];
        const u16* Vs = Vb[t & 1];
        // S^T = K(64kv x 64d) . Q^T(64d x 32q); ak transient per-ks (VGPR cap)
        f32x4 sf[2][4];                  // [mt][nt]
        #pragma unroll
        for (int mt = 0; mt < 2; ++mt)
            #pragma unroll
            for (int nt = 0; nt < 4; ++nt) sf[mt][nt] = (f32x4){0.f, 0.f, 0.f, 0.f};
        #pragma unroll
        for (int ks = 0; ks < 2; ++ks){
            bf16x8 ak[4];
            #pragma unroll
            for (int nt = 0; nt < 4; ++nt)
                ak[nt] = ldfrag(&Kt[(nt*16 + l15) * 64 + (((ks*4 + quad) ^ swz) * 8)]);
            #pragma unroll
            for (int mt = 0; mt < 2; ++mt)
                #pragma unroll
                for (int nt = 0; nt < 4; ++nt)
                    sf[mt][nt] = MFMA(ak[nt], qf[mt][ks], sf[mt][nt]);
        }
        // lane holds (kv = nt*16+quad*4+r, q = mt*16+l15): exp2, packed P
        #pragma unroll
        for (int mt = 0; mt < 2; ++mt)
            #pragma unroll
            for (int nt = 0; nt < 4; ++nt){
                float e0 = EXP2(sf[mt][nt][0]);
                float e1 = EXP2(sf[mt][nt][1]);
                float e2 = EXP2(sf[mt][nt][2]);
                float e3 = EXP2(sf[mt][nt][3]);
                *(uint2*)&pw[(mt*16 + l15) * PST + nt*16 + quad*4] =
                    make_uint2(pk2(e0, e1), pk2(e2, e3));
            }
        __threadfence_block();           // P LDS write->read order (wave-local)
        // O^T += V^T(64d x 64kv) . P(64kv x 32q); sums += ones . P
        #pragma unroll
        for (int ks = 0; ks < 2; ++ks){
            bf16x8 av[4], bp[2];
            #pragma unroll
            for (int dt = 0; dt < 4; ++dt)
                av[dt] = ldfrag(&Vs[(dt*16 + l15) * 64 + (((ks*4 + quad) ^ swz) * 8)]);
            #pragma unroll
            for (int mt = 0; mt < 2; ++mt)
                bp[mt] = ld2x64(&pw[(mt*16 + l15) * PST + ks*32 + quad*8]);
            #pragma unroll
            for (int mt = 0; mt < 2; ++mt)
                sums[mt] = MFMA(ones, bp[mt], sums[mt]);
            #pragma unroll
            for (int dt = 0; dt < 4; ++dt)
                #pragma unroll
                for (int mt = 0; mt < 2; ++mt)
                    O[dt][mt] = MFMA(av[dt], bp[mt], O[dt][mt]);
        }
    }
    // epilogue: every reg/quad of sums[mt] holds the row-sum for its q col
    #pragma unroll
    for (int mt = 0; mt < 2; ++mt){
        float inv = 1.0f / sums[mt][0];
        size_t row = (size_t)(b * S + q0 + wave*32 + mt*16 + l15);
        #pragma unroll
        for (int dt = 0; dt < 4; ++dt){
            u32 lo = pk2(O[dt][mt][0] * inv, O[dt][mt][1] * inv);
            u32 hi = pk2(O[dt][mt][2] * inv, O[dt][mt][3] * inv);
            *(uint2*)(AO + row * Dm + h * 64 + dt*16 + quad*4) = make_uint2(lo, hi);
        }
    }
}

extern "C" void kernel_launch(void* const* d_in, const int* in_sizes, int n_in,
                              void* d_out, int out_size, void* d_ws, size_t ws_size,
                              hipStream_t stream){
    const float* q  = (const float*)d_in[0];
    const float* k  = (const float*)d_in[1];
    const float* v  = (const float*)d_in[2];
    const float* Wq = (const float*)d_in[3];
    const float* Wk = (const float*)d_in[4];
    const float* Wv = (const float*)d_in[5];
    const float* Wo = (const float*)d_in[6];
    char* ws = (char*)d_ws;
    const size_t MB = 1u << 20;
    u16* WqT = (u16*)(ws);               // [1024][1024]  2 MiB
    u16* WkT = (u16*)(ws + 2*MB);        // [ 256][1024]  0.5
    u16* WvT = (u16*)(ws + 2*MB + 512*1024);
    u16* WoT = (u16*)(ws + 3*MB);        // 2 MiB
    u16* Qp  = (u16*)(ws + 5*MB);        // Q-proj      16 MiB
    u16* Kp  = (u16*)(ws + 21*MB);       // K-proj       4 MiB
    u16* Vt  = (u16*)(ws + 25*MB);       // V-proj^T     4 MiB
    u16* AO  = (u16*)(ws + 29*MB);       // attn out    16 MiB

    const float cexp = 0.125f * 1.44269504f;   // softmax scale * log2(e)

    prep<<<dim3(2560), 256, 0, stream>>>(Wq, Wk, Wv, Wo, WqT, WkT, WvT, WoT);
    gemm_qkv<<<dim3(768), 256, 0, stream>>>(q, WqT, Qp, k, WkT, Kp,
                                            v, WvT, Vt, cexp);
    attn_k<<<dim3(8, 16, 4), 512, 0, stream>>>(Qp, Kp, Vt, AO);
    gemm_o<<<dim3(512), 256, 0, stream>>>(AO, WoT, (float*)d_out);
}